// Round 2
// baseline (191.346 us; speedup 1.0000x reference)
//
#include <hip/hip_runtime.h>
#include <stdint.h>

typedef unsigned short u16t;
typedef unsigned int   u32t;
typedef __attribute__((ext_vector_type(8))) short short8;
typedef __attribute__((ext_vector_type(4))) float f32x4;

__device__ __forceinline__ float bf2f(u16t h){
  union { u32t u; float f; } c; c.u = ((u32t)h) << 16; return c.f;
}
// round-to-nearest-even f32 -> bf16 bits
__device__ __forceinline__ u16t f2bf(float f){
  union { float f; u32t u; } c; c.f = f;
  u32t u = c.u;
  u = u + 0x7fffu + ((u >> 16) & 1u);
  return (u16t)(u >> 16);
}
__device__ __forceinline__ u32t pk2(float a, float b){
  return (u32t)f2bf(a) | ((u32t)f2bf(b) << 16);
}

// dtype-generic loads ------------------------------------------------------
template<bool BF>
__device__ __forceinline__ float ldv(const void* p, size_t i){
  if constexpr (BF) return bf2f(((const u16t*)p)[i]);
  else              return ((const float*)p)[i];
}
template<bool BF>
__device__ __forceinline__ void ld8(const void* p, size_t i, float* v){
  if constexpr (BF){
    uint4 u = *(const uint4*)((const u16t*)p + i);
    const u32t a[4] = {u.x, u.y, u.z, u.w};
#pragma unroll
    for (int d = 0; d < 4; ++d){
      v[2*d]   = bf2f((u16t)(a[d] & 0xffffu));
      v[2*d+1] = bf2f((u16t)(a[d] >> 16));
    }
  } else {
    const float4* q = (const float4*)((const float*)p + i);
    float4 A = q[0], B = q[1];
    v[0]=A.x; v[1]=A.y; v[2]=A.z; v[3]=A.w;
    v[4]=B.x; v[5]=B.y; v[6]=B.z; v[7]=B.w;
  }
}
// 8 elements -> 4 packed bf16 pairs
template<bool BF>
__device__ __forceinline__ void ld8pk(const void* p, size_t i, u32t* dst){
  if constexpr (BF){
    uint4 u = *(const uint4*)((const u16t*)p + i);
    dst[0]=u.x; dst[1]=u.y; dst[2]=u.z; dst[3]=u.w;
  } else {
    const float4* q = (const float4*)((const float*)p + i);
    float4 A = q[0], B = q[1];
    dst[0] = pk2(A.x, A.y); dst[1] = pk2(A.z, A.w);
    dst[2] = pk2(B.x, B.y); dst[3] = pk2(B.z, B.w);
  }
}

// ---------------------------------------------------------------------------
// probe: decide bf16 (flag=1) vs f32 (flag=0) from exponent-field statistics
// ---------------------------------------------------------------------------
__global__ void k_probe(const void* xv, int* flag){
  __shared__ int cnt;
  const int t = threadIdx.x;           // 128 threads
  if (t == 0) cnt = 0;
  __syncthreads();
  u16t h = ((const u16t*)xv)[t];
  int e = (h >> 7) & 0xff;
  if (e >= 90 && e <= 150) atomicAdd(&cnt, 1);
  __syncthreads();
  if (t == 0) *flag = (cnt >= 104) ? 1 : 0;
}

// ---------------------------------------------------------------------------
// K1: t1[b,c,i,j] = 1x1 conv + bias (fp32 into ws). grid 512=(b,i,j), blk 128=c
// ---------------------------------------------------------------------------
template<bool BF>
__device__ __forceinline__ void conv1_body(
    const void* x, const void* w, const void* bias, float* t1)
{
  __shared__ float xs[256];
  const int bid = blockIdx.x;
  const int b = bid >> 8, i = (bid >> 4) & 15, j = bid & 15;
  const int t = threadIdx.x;
  const size_t base = (size_t)b * 65536 + i * 16 + j;
  xs[t]       = ldv<BF>(x, base + (size_t)t * 256);
  xs[t + 128] = ldv<BF>(x, base + (size_t)(t + 128) * 256);
  __syncthreads();
  float acc = ldv<BF>(bias, t);
  for (int k = 0; k < 256; k += 8){
    float wv[8];
    ld8<BF>(w, (size_t)t * 256 + k, wv);
#pragma unroll
    for (int d = 0; d < 8; ++d) acc += xs[k + d] * wv[d];
  }
  t1[((size_t)(b * 128 + t) * 16 + i) * 16 + j] = acc;
}
__global__ __launch_bounds__(128) void k_conv1(
    const void* x, const void* w, const void* bias, float* t1, const int* flag){
  if (*flag) conv1_body<true >(x, w, bias, t1);
  else       conv1_body<false>(x, w, bias, t1);
}

// ---------------------------------------------------------------------------
// K2: dw3x3 + BN + StarReLU + channel_expand + StarReLU -> wdec[512][8] fp32
// ---------------------------------------------------------------------------
template<bool BF>
__device__ __forceinline__ void wdec_body(
    const float* t1, const void* dww, const void* dwb,
    const void* bng, const void* bnb, const void* bnm, const void* bnv,
    const void* s1s, const void* s1b, const void* cew, const void* ceb,
    const void* s2s, const void* s2b, float* wdec)
{
  __shared__ float vs[128];
  const int bid = blockIdx.x;
  const int b = bid >> 8, i = (bid >> 4) & 15, j = bid & 15;
  const int c = threadIdx.x;
  float s = ldv<BF>(dwb, c);
  const float* tb = t1 + (size_t)(b * 128 + c) * 256;
#pragma unroll
  for (int di = 0; di < 3; ++di){
    const int ii = i + di - 1;
    if (ii < 0 || ii > 15) continue;
#pragma unroll
    for (int dj = 0; dj < 3; ++dj){
      const int jj = j + dj - 1;
      if (jj < 0 || jj > 15) continue;
      s += tb[ii * 16 + jj] * ldv<BF>(dww, c * 9 + di * 3 + dj);
    }
  }
  float v = ldv<BF>(bng, c) * (s - ldv<BF>(bnm, c)) *
            rsqrtf(ldv<BF>(bnv, c) + 1e-5f) + ldv<BF>(bnb, c);
  float rl = fmaxf(v, 0.0f);
  vs[c] = ldv<BF>(s1s, 0) * rl * rl + ldv<BF>(s1b, 0);
  __syncthreads();
  if (c < 8){
    float a = ldv<BF>(ceb, c);
    for (int k = 0; k < 128; ++k) a += vs[k] * ldv<BF>(cew, c * 128 + k);
    float r2 = fmaxf(a, 0.0f);
    wdec[bid * 8 + c] = ldv<BF>(s2s, 0) * r2 * r2 + ldv<BF>(s2b, 0);
  }
}
__global__ __launch_bounds__(128) void k_wdec(
    const float* t1, const void* dww, const void* dwb,
    const void* bng, const void* bnb, const void* bnm, const void* bnv,
    const void* s1s, const void* s1b, const void* cew, const void* ceb,
    const void* s2s, const void* s2b, float* wdec, const int* flag){
  if (*flag) wdec_body<true >(t1,dww,dwb,bng,bnb,bnm,bnv,s1s,s1b,cew,ceb,s2s,s2b,wdec);
  else       wdec_body<false>(t1,dww,dwb,bng,bnb,bnm,bnv,s1s,s1b,cew,ceb,s2s,s2b,wdec);
}

// ---------------------------------------------------------------------------
// K3: main hyper-GEMM. grid (128, 4): x=(b,i,j-group of 4), y=e-chunk of 64.
// block 256 = 4 waves. LDS: Y^T [4 g][64 pq][256 o] bf16, row-rotated
// (phys_col = (o + row*8) & 255) = 128 KB. One barrier total.
// ---------------------------------------------------------------------------
template<bool BF>
__device__ __forceinline__ void main_body(
    const void* y, const void* wbase, const float* wdec, void* out, u16t* smem)
{
  const int gx  = blockIdx.x;
  const int ec  = blockIdx.y;
  const int b   = gx >> 6;
  const int i   = (gx >> 2) & 15;
  const int j0  = (gx & 3) * 4;
  const int tid = threadIdx.x;

  // ---- stage: 4 y patches -> LDS [g][pq][o] via in-register 8x8 transpose
  {
    const int o_oct = tid & 31;   // o block of 8
    const int p     = tid >> 5;   // 0..7
#pragma unroll
    for (int g = 0; g < 4; ++g){
      u32t Rp[8][4];              // Rp[r][d] = bf16 pair (q=2d, q=2d+1) of o-row r
#pragma unroll
      for (int r = 0; r < 8; ++r){
        const size_t idx = (((size_t)(b * 256 + o_oct * 8 + r)) * 128 + (i * 8 + p)) * 128
                         + (j0 + g) * 8;
        ld8pk<BF>(y, idx, Rp[r]);
      }
#pragma unroll
      for (int q = 0; q < 8; ++q){
        const int d = q >> 1, h = q & 1;
        u32t cc[4];
#pragma unroll
        for (int k = 0; k < 4; ++k){
          const u32t lo32 = Rp[2*k][d], hi32 = Rp[2*k+1][d];
          cc[k] = h ? ((lo32 >> 16)     | (hi32 & 0xffff0000u))
                    : ((lo32 & 0xffffu) | (hi32 << 16));
        }
        const int row  = g * 64 + p * 8 + q;
        const int phys = (o_oct * 8 + row * 8) & 255;        // rotation swizzle
        *(uint4*)(smem + row * 256 + phys) = make_uint4(cc[0], cc[1], cc[2], cc[3]);
      }
    }
  }
  __syncthreads();   // the only barrier

  // ---- wdec (fp32, tiny)
  float wd[4][8];
#pragma unroll
  for (int g = 0; g < 4; ++g){
    const float* wp = wdec + (size_t)(b * 256 + i * 16 + j0 + g) * 8;
#pragma unroll
    for (int f = 0; f < 8; ++f) wd[g][f] = wp[f];
  }

  const int wave = tid >> 6, lane = tid & 63;
  const int l15 = lane & 15, l4 = lane >> 4;
  const int e_a = ec * 64 + wave * 16 + l15;          // A-fragment row (m)
  const size_t wb_off = (size_t)e_a * 2048 + (size_t)l4 * 64;

  f32x4 acc[4][4];
#pragma unroll
  for (int g = 0; g < 4; ++g)
#pragma unroll
    for (int nt = 0; nt < 4; ++nt)
      acc[g][nt] = (f32x4){0.f, 0.f, 0.f, 0.f};

  u32t Wb[2][8][4];
#pragma unroll
  for (int m = 0; m < 8; ++m) ld8pk<BF>(wbase, wb_off + m * 8, Wb[0][m]);

#pragma unroll
  for (int ks = 0; ks < 8; ++ks){
    const int cur = ks & 1;
    if (ks < 7){
#pragma unroll
      for (int m = 0; m < 8; ++m)
        ld8pk<BF>(wbase, wb_off + (size_t)(ks + 1) * 256 + m * 8, Wb[cur ^ 1][m]);
    }
    float s[4][8];
#pragma unroll
    for (int m = 0; m < 8; ++m){
      float wf[8];
#pragma unroll
      for (int d = 0; d < 4; ++d){
        wf[2*d]   = bf2f((u16t)(Wb[cur][m][d] & 0xffffu));
        wf[2*d+1] = bf2f((u16t)(Wb[cur][m][d] >> 16));
      }
#pragma unroll
      for (int g = 0; g < 4; ++g){
        float t = 0.f;
#pragma unroll
        for (int f = 0; f < 8; ++f) t += wf[f] * wd[g][f];
        s[g][m] = t;
      }
    }
#pragma unroll
    for (int g = 0; g < 4; ++g){
      short8 af;
#pragma unroll
      for (int m = 0; m < 8; ++m) af[m] = (short)f2bf(s[g][m]);
#pragma unroll
      for (int nt = 0; nt < 4; ++nt){
        const int row = g * 64 + nt * 16 + l15;       // B-frag: n = lane&15
        const int c0  = (ks * 32 + l4 * 8 + row * 8) & 255;
        const short8 bfr = *(const short8*)(smem + row * 256 + c0);
        acc[g][nt] = __builtin_amdgcn_mfma_f32_16x16x32_bf16(af, bfr, acc[g][nt], 0, 0, 0);
      }
    }
  }

  // ---- epilogue: C/D layout col=lane&15, row=(lane>>4)*4+reg
#pragma unroll
  for (int g = 0; g < 4; ++g){
#pragma unroll
    for (int nt = 0; nt < 4; ++nt){
      const int col = nt * 16 + l15;
      const int pp = col >> 3, qq = col & 7;
#pragma unroll
      for (int r = 0; r < 4; ++r){
        const int ee = ec * 64 + wave * 16 + l4 * 4 + r;
        const size_t oaddr = ((size_t)(b * 256 + ee) * 128 + (i * 8 + pp)) * 128
                           + (j0 + g) * 8 + qq;
        const float v = acc[g][nt][r];
        if constexpr (BF) ((u16t*)out)[oaddr] = f2bf(v);
        else              ((float*)out)[oaddr] = v;
      }
    }
  }
}
__global__ __launch_bounds__(256, 1) void k_main(
    const void* y, const void* wbase, const float* wdec, void* out, const int* flag){
  extern __shared__ __align__(16) u16t smem[];
  if (*flag) main_body<true >(y, wbase, wdec, out, smem);
  else       main_body<false>(y, wbase, wdec, out, smem);
}

// ---------------------------------------------------------------------------
extern "C" void kernel_launch(void* const* d_in, const int* in_sizes, int n_in,
                              void* d_out, int out_size, void* d_ws, size_t ws_size,
                              hipStream_t stream)
{
  float* t1   = (float*)d_ws;                       // 65536 floats
  float* wdec = (float*)d_ws + 65536;               // 4096 floats
  int*   flag = (int*)((char*)d_ws + 278528);       // 4 bytes

  k_probe<<<dim3(1), dim3(128), 0, stream>>>(d_in[0], flag);
  k_conv1<<<dim3(512), dim3(128), 0, stream>>>(d_in[0], d_in[2], d_in[3], t1, flag);
  k_wdec<<<dim3(512), dim3(128), 0, stream>>>(t1, d_in[4], d_in[5], d_in[6], d_in[7],
                                              d_in[8], d_in[9], d_in[10], d_in[11],
                                              d_in[12], d_in[13], d_in[14], d_in[15],
                                              wdec, flag);

  const int lds_bytes = 4 * 64 * 256 * 2;           // 131072
  hipFuncSetAttribute((const void*)k_main,
                      hipFuncAttributeMaxDynamicSharedMemorySize, lds_bytes);
  k_main<<<dim3(128, 4), dim3(256), lds_bytes, stream>>>(d_in[1], d_in[16], wdec,
                                                         d_out, flag);
}

// Round 3
// 179.463 us; speedup vs baseline: 1.0662x; 1.0662x over previous
//
#include <hip/hip_runtime.h>
#include <stdint.h>

typedef unsigned short u16t;
typedef unsigned int   u32t;
typedef _Float16       h16;
typedef __attribute__((ext_vector_type(2))) _Float16 h16x2;
typedef __attribute__((ext_vector_type(8))) short short8;
typedef __attribute__((ext_vector_type(4))) float f32x4;

#if defined(__has_builtin)
#if __has_builtin(__builtin_amdgcn_fdot2)
#define HAVE_DOT2 1
#endif
#endif

__device__ __forceinline__ float dot2h(u32t a, u32t b, float c){
#ifdef HAVE_DOT2
  return __builtin_amdgcn_fdot2(__builtin_bit_cast(h16x2, a),
                                __builtin_bit_cast(h16x2, b), c, false);
#else
  h16x2 ha = __builtin_bit_cast(h16x2, a), hb = __builtin_bit_cast(h16x2, b);
  return c + (float)ha[0]*(float)hb[0] + (float)ha[1]*(float)hb[1];
#endif
}

__device__ __forceinline__ float bf2f(u16t h){
  union { u32t u; float f; } c; c.u = ((u32t)h) << 16; return c.f;
}
__device__ __forceinline__ u16t f2bf(float f){
  union { float f; u32t u; } c; c.f = f;
  u32t u = c.u;
  u = u + 0x7fffu + ((u >> 16) & 1u);
  return (u16t)(u >> 16);
}
__device__ __forceinline__ u32t pk2bf(float a, float b){
  return (u32t)f2bf(a) | ((u32t)f2bf(b) << 16);
}
__device__ __forceinline__ u32t pk2h(float a, float b){
  h16x2 h = { (h16)a, (h16)b };
  return __builtin_bit_cast(u32t, h);
}

// dtype-generic loads ------------------------------------------------------
template<bool BF>
__device__ __forceinline__ float ldv(const void* p, size_t i){
  if constexpr (BF) return bf2f(((const u16t*)p)[i]);
  else              return ((const float*)p)[i];
}
template<bool BF>
__device__ __forceinline__ void ld8(const void* p, size_t i, float* v){
  if constexpr (BF){
    uint4 u = *(const uint4*)((const u16t*)p + i);
    const u32t a[4] = {u.x, u.y, u.z, u.w};
#pragma unroll
    for (int d = 0; d < 4; ++d){
      v[2*d]   = bf2f((u16t)(a[d] & 0xffffu));
      v[2*d+1] = bf2f((u16t)(a[d] >> 16));
    }
  } else {
    const float4* q = (const float4*)((const float*)p + i);
    float4 A = q[0], B = q[1];
    v[0]=A.x; v[1]=A.y; v[2]=A.z; v[3]=A.w;
    v[4]=B.x; v[5]=B.y; v[6]=B.z; v[7]=B.w;
  }
}
// 8 elements -> 4 packed bf16 pairs
template<bool BF>
__device__ __forceinline__ void ld8pk(const void* p, size_t i, u32t* dst){
  if constexpr (BF){
    uint4 u = *(const uint4*)((const u16t*)p + i);
    dst[0]=u.x; dst[1]=u.y; dst[2]=u.z; dst[3]=u.w;
  } else {
    const float4* q = (const float4*)((const float*)p + i);
    float4 A = q[0], B = q[1];
    dst[0] = pk2bf(A.x, A.y); dst[1] = pk2bf(A.z, A.w);
    dst[2] = pk2bf(B.x, B.y); dst[3] = pk2bf(B.z, B.w);
  }
}

// ---------------------------------------------------------------------------
// probe: bf16 (flag=1) vs f32 (flag=0)
// ---------------------------------------------------------------------------
__global__ void k_probe(const void* xv, int* flag){
  __shared__ int cnt;
  const int t = threadIdx.x;
  if (t == 0) cnt = 0;
  __syncthreads();
  u16t h = ((const u16t*)xv)[t];
  int e = (h >> 7) & 0xff;
  if (e >= 90 && e <= 150) atomicAdd(&cnt, 1);
  __syncthreads();
  if (t == 0) *flag = (cnt >= 104) ? 1 : 0;
}

// ---------------------------------------------------------------------------
// P1: conv1 + dw3x3 + BN + StarReLU -> t2[b,c,ij] f32
// grid (64 cgrp, 2 b), block 256 = ij. 2 channels per block.
// ---------------------------------------------------------------------------
template<bool BF>
__device__ __forceinline__ void pre12_body(
    const void* x, const void* w, const void* bias,
    const void* dww, const void* dwb,
    const void* bng, const void* bnb, const void* bnm, const void* bnv,
    const void* s1s, const void* s1b, float* t2)
{
  __shared__ float ts[2][256];
  const int cg = blockIdx.x, b = blockIdx.y;
  const int ij = threadIdx.x, i = ij >> 4, j = ij & 15;
  const int c0 = cg * 2;
  float a0 = ldv<BF>(bias, c0), a1 = ldv<BF>(bias, c0 + 1);
  const size_t xb = (size_t)b * 65536 + ij;
#pragma unroll 8
  for (int k = 0; k < 256; ++k){
    const float xv = ldv<BF>(x, xb + (size_t)k * 256);
    a0 += xv * ldv<BF>(w, (size_t)c0 * 256 + k);
    a1 += xv * ldv<BF>(w, (size_t)(c0 + 1) * 256 + k);
  }
  ts[0][ij] = a0;
  ts[1][ij] = a1;
  __syncthreads();
  const float sc1 = ldv<BF>(s1s, 0), sb1 = ldv<BF>(s1b, 0);
#pragma unroll
  for (int cc = 0; cc < 2; ++cc){
    const int c = c0 + cc;
    float s = ldv<BF>(dwb, c);
#pragma unroll
    for (int di = 0; di < 3; ++di){
      const int ii = i + di - 1;
      if (ii < 0 || ii > 15) continue;
#pragma unroll
      for (int dj = 0; dj < 3; ++dj){
        const int jj = j + dj - 1;
        if (jj < 0 || jj > 15) continue;
        s += ts[cc][ii * 16 + jj] * ldv<BF>(dww, c * 9 + di * 3 + dj);
      }
    }
    const float v = ldv<BF>(bng, c) * (s - ldv<BF>(bnm, c)) *
                    rsqrtf(ldv<BF>(bnv, c) + 1e-5f) + ldv<BF>(bnb, c);
    const float r = fmaxf(v, 0.0f);
    t2[((size_t)b * 128 + c) * 256 + ij] = sc1 * r * r + sb1;
  }
}
__global__ __launch_bounds__(256) void k_pre12(
    const void* x, const void* w, const void* bias,
    const void* dww, const void* dwb,
    const void* bng, const void* bnb, const void* bnm, const void* bnv,
    const void* s1s, const void* s1b, float* t2, const int* flag){
  if (*flag) pre12_body<true >(x,w,bias,dww,dwb,bng,bnb,bnm,bnv,s1s,s1b,t2);
  else       pre12_body<false>(x,w,bias,dww,dwb,bng,bnb,bnm,bnv,s1s,s1b,t2);
}

// ---------------------------------------------------------------------------
// P3: channel_expand + StarReLU -> wdecf[512][8] f32 and (optionally) packed
// f16 pairs wdech[512] uint4. grid (2 b), block 256 = ij.
// ---------------------------------------------------------------------------
template<bool BF>
__device__ __forceinline__ void pre3_body(
    const float* t2, const void* cew, const void* ceb,
    const void* s2s, const void* s2b, float* wdecf, uint4* wdech)
{
  const int b = blockIdx.x, ij = threadIdx.x;
  float a[8];
#pragma unroll
  for (int f = 0; f < 8; ++f) a[f] = ldv<BF>(ceb, f);
#pragma unroll 4
  for (int c = 0; c < 128; ++c){
    const float tv = t2[((size_t)b * 128 + c) * 256 + ij];
#pragma unroll
    for (int f = 0; f < 8; ++f) a[f] += tv * ldv<BF>(cew, f * 128 + c);
  }
  const float sc2 = ldv<BF>(s2s, 0), sb2 = ldv<BF>(s2b, 0);
  float o[8];
#pragma unroll
  for (int f = 0; f < 8; ++f){
    const float r = fmaxf(a[f], 0.0f);
    o[f] = sc2 * r * r + sb2;
  }
  const int idx = b * 256 + ij;
#pragma unroll
  for (int f = 0; f < 8; ++f) wdecf[idx * 8 + f] = o[f];
  if (wdech){
    wdech[idx] = make_uint4(pk2h(o[0], o[1]), pk2h(o[2], o[3]),
                            pk2h(o[4], o[5]), pk2h(o[6], o[7]));
  }
}
__global__ __launch_bounds__(256) void k_pre3(
    const float* t2, const void* cew, const void* ceb,
    const void* s2s, const void* s2b, float* wdecf, uint4* wdech, const int* flag){
  if (*flag) pre3_body<true >(t2, cew, ceb, s2s, s2b, wdecf, wdech);
  else       pre3_body<false>(t2, cew, ceb, s2s, s2b, wdecf, wdech);
}

// ---------------------------------------------------------------------------
// PW: W_base -> packed f16 pairs. 65536 rows of 8. grid 256, block 256.
// ---------------------------------------------------------------------------
template<bool BF>
__device__ __forceinline__ void prew_body(const void* wb, uint4* wbh){
  const int t = blockIdx.x * 256 + threadIdx.x;   // row index, < 65536
  float v[8];
  ld8<BF>(wb, (size_t)t * 8, v);
  wbh[t] = make_uint4(pk2h(v[0], v[1]), pk2h(v[2], v[3]),
                      pk2h(v[4], v[5]), pk2h(v[6], v[7]));
}
__global__ __launch_bounds__(256) void k_prew(const void* wb, uint4* wbh, const int* flag){
  if (*flag) prew_body<true >(wb, wbh);
  else       prew_body<false>(wb, wbh);
}

// ---------------------------------------------------------------------------
// K3: main hyper-GEMM. grid (128, 2): x = (b, i, j-group of 4), y = e-chunk 128.
// block 512 = 8 waves; wave w -> e-tile [ec*128 + w*16, +16).
// LDS: Y^T [4 g][64 pq][256 o] bf16, rotation swizzle, 128 KB. One barrier.
// PREW: A-gen from packed-f16 W_base via v_dot2_f32_f16.
// ---------------------------------------------------------------------------
template<bool BF, bool PREW>
__device__ __forceinline__ void main_body(
    const void* y, const void* wbase, const uint4* wbh,
    const float* wdecf, const uint4* wdech, void* out, u16t* smem)
{
  const int gx  = blockIdx.x;
  const int ec  = blockIdx.y;
  const int b   = gx >> 6;
  const int i   = (gx >> 2) & 15;
  const int j0  = (gx & 3) * 4;
  const int tid = threadIdx.x;

  // ---- stage: 4 y patches -> LDS [g][pq][o] via in-register 8x8 transpose
  {
    const int o_oct = tid & 31;
    const int p     = (tid >> 5) & 7;
    const int gh    = tid >> 8;           // 0/1 -> handles g = 2*gh, 2*gh+1
#pragma unroll
    for (int gi = 0; gi < 2; ++gi){
      const int g = gh * 2 + gi;
      u32t Rp[8][4];
#pragma unroll
      for (int r = 0; r < 8; ++r){
        const size_t idx = (((size_t)(b * 256 + o_oct * 8 + r)) * 128 + (i * 8 + p)) * 128
                         + (j0 + g) * 8;
        ld8pk<BF>(y, idx, Rp[r]);
      }
#pragma unroll
      for (int q = 0; q < 8; ++q){
        const int d = q >> 1, h = q & 1;
        u32t cc[4];
#pragma unroll
        for (int k = 0; k < 4; ++k){
          const u32t lo32 = Rp[2*k][d], hi32 = Rp[2*k+1][d];
          cc[k] = h ? ((lo32 >> 16)     | (hi32 & 0xffff0000u))
                    : ((lo32 & 0xffffu) | (hi32 << 16));
        }
        const int row  = g * 64 + p * 8 + q;
        const int phys = (o_oct * 8 + row * 8) & 255;
        *(uint4*)(smem + row * 256 + phys) = make_uint4(cc[0], cc[1], cc[2], cc[3]);
      }
    }
  }
  __syncthreads();   // the only barrier

  const int wave = tid >> 6, lane = tid & 63;
  const int l15 = lane & 15, l4 = lane >> 4;
  const int e0  = ec * 128 + wave * 16;
  const int e_a = e0 + l15;

  // wdec per g
  u32t wdp[4][4];      // packed f16 pairs (PREW)
  float wdf[4][8];     // f32 (fallback)
#pragma unroll
  for (int g = 0; g < 4; ++g){
    const int loc = b * 256 + i * 16 + j0 + g;
    if constexpr (PREW){
      const uint4 q = wdech[loc];
      wdp[g][0] = q.x; wdp[g][1] = q.y; wdp[g][2] = q.z; wdp[g][3] = q.w;
    } else {
#pragma unroll
      for (int f = 0; f < 8; ++f) wdf[g][f] = wdecf[loc * 8 + f];
    }
  }

  f32x4 acc[4][4];
#pragma unroll
  for (int g = 0; g < 4; ++g)
#pragma unroll
    for (int nt = 0; nt < 4; ++nt)
      acc[g][nt] = (f32x4){0.f, 0.f, 0.f, 0.f};

  // W rows for this lane: mi-th row of K-quad l4 at o-chunk ks
  const uint4* wb4 = wbh + (size_t)e_a * 256 + l4 * 8;   // PREW path
  const size_t wb_off = (size_t)e_a * 2048 + (size_t)l4 * 64;  // elements, fallback

  u32t Wb[2][8][4];
#pragma unroll
  for (int m = 0; m < 8; ++m){
    if constexpr (PREW){
      const uint4 q = wb4[m];
      Wb[0][m][0]=q.x; Wb[0][m][1]=q.y; Wb[0][m][2]=q.z; Wb[0][m][3]=q.w;
    } else {
      ld8pk<BF>(wbase, wb_off + m * 8, Wb[0][m]);
    }
  }

#pragma unroll
  for (int ks = 0; ks < 8; ++ks){
    const int cur = ks & 1;
    if (ks < 7){
#pragma unroll
      for (int m = 0; m < 8; ++m){
        if constexpr (PREW){
          const uint4 q = wb4[(ks + 1) * 32 + m];
          Wb[cur^1][m][0]=q.x; Wb[cur^1][m][1]=q.y; Wb[cur^1][m][2]=q.z; Wb[cur^1][m][3]=q.w;
        } else {
          ld8pk<BF>(wbase, wb_off + (size_t)(ks + 1) * 256 + m * 8, Wb[cur^1][m]);
        }
      }
    }
    float s[4][8];
#pragma unroll
    for (int m = 0; m < 8; ++m){
      if constexpr (PREW){
#pragma unroll
        for (int g = 0; g < 4; ++g){
          float t = 0.f;
#pragma unroll
          for (int d = 0; d < 4; ++d) t = dot2h(Wb[cur][m][d], wdp[g][d], t);
          s[g][m] = t;
        }
      } else {
        float wf[8];
#pragma unroll
        for (int d = 0; d < 4; ++d){
          wf[2*d]   = bf2f((u16t)(Wb[cur][m][d] & 0xffffu));
          wf[2*d+1] = bf2f((u16t)(Wb[cur][m][d] >> 16));
        }
#pragma unroll
        for (int g = 0; g < 4; ++g){
          float t = 0.f;
#pragma unroll
          for (int f = 0; f < 8; ++f) t += wf[f] * wdf[g][f];
          s[g][m] = t;
        }
      }
    }
#pragma unroll
    for (int g = 0; g < 4; ++g){
      short8 af;
#pragma unroll
      for (int m = 0; m < 8; ++m) af[m] = (short)f2bf(s[g][m]);
#pragma unroll
      for (int nt = 0; nt < 4; ++nt){
        const int row = g * 64 + nt * 16 + l15;
        const int c0  = (ks * 32 + l4 * 8 + row * 8) & 255;
        const short8 bfr = *(const short8*)(smem + row * 256 + c0);
        acc[g][nt] = __builtin_amdgcn_mfma_f32_16x16x32_bf16(af, bfr, acc[g][nt], 0, 0, 0);
      }
    }
  }

  // ---- epilogue: C/D layout col=lane&15, row=(lane>>4)*4+reg
#pragma unroll
  for (int g = 0; g < 4; ++g){
#pragma unroll
    for (int nt = 0; nt < 4; ++nt){
      const int col = nt * 16 + l15;
      const int pp = col >> 3, qq = col & 7;
#pragma unroll
      for (int r = 0; r < 4; ++r){
        const int ee = e0 + l4 * 4 + r;
        const size_t oaddr = ((size_t)(b * 256 + ee) * 128 + (i * 8 + pp)) * 128
                           + (j0 + g) * 8 + qq;
        const float v = acc[g][nt][r];
        if constexpr (BF) ((u16t*)out)[oaddr] = f2bf(v);
        else              ((float*)out)[oaddr] = v;
      }
    }
  }
}

__global__ __launch_bounds__(512, 2) void k_main_pw(
    const void* y, const uint4* wbh, const uint4* wdech, void* out, const int* flag){
  extern __shared__ __align__(16) u16t smem[];
  if (*flag) main_body<true , true>(y, nullptr, wbh, nullptr, wdech, out, smem);
  else       main_body<false, true>(y, nullptr, wbh, nullptr, wdech, out, smem);
}
__global__ __launch_bounds__(512, 2) void k_main_npw(
    const void* y, const void* wbase, const float* wdecf, void* out, const int* flag){
  extern __shared__ __align__(16) u16t smem[];
  if (*flag) main_body<true , false>(y, wbase, nullptr, wdecf, nullptr, out, smem);
  else       main_body<false, false>(y, wbase, nullptr, wdecf, nullptr, out, smem);
}

// ---------------------------------------------------------------------------
extern "C" void kernel_launch(void* const* d_in, const int* in_sizes, int n_in,
                              void* d_out, int out_size, void* d_ws, size_t ws_size,
                              hipStream_t stream)
{
  // ws layout
  float* t2    = (float*)d_ws;                           // 262144 B
  float* wdecf = (float*)((char*)d_ws + 262144);         // 16384 B
  int*   flag  = (int*)((char*)d_ws + 278528);           // 4 B
  uint4* wdech = (uint4*)((char*)d_ws + 278544);         // 8192 B
  uint4* wbh   = (uint4*)((char*)d_ws + 286736);         // 1048576 B
  const bool prew = (ws_size >= 286736u + 1048576u);

  k_probe<<<dim3(1), dim3(128), 0, stream>>>(d_in[0], flag);
  k_pre12<<<dim3(64, 2), dim3(256), 0, stream>>>(
      d_in[0], d_in[2], d_in[3], d_in[4], d_in[5], d_in[6], d_in[7],
      d_in[8], d_in[9], d_in[10], d_in[11], t2, flag);
  k_pre3<<<dim3(2), dim3(256), 0, stream>>>(
      t2, d_in[12], d_in[13], d_in[14], d_in[15], wdecf,
      prew ? wdech : (uint4*)nullptr, flag);

  const int lds_bytes = 4 * 64 * 256 * 2;   // 131072
  if (prew){
    k_prew<<<dim3(256), dim3(256), 0, stream>>>(d_in[16], wbh, flag);
    hipFuncSetAttribute((const void*)k_main_pw,
                        hipFuncAttributeMaxDynamicSharedMemorySize, lds_bytes);
    k_main_pw<<<dim3(128, 2), dim3(512), lds_bytes, stream>>>(
        d_in[1], wbh, wdech, d_out, flag);
  } else {
    hipFuncSetAttribute((const void*)k_main_npw,
                        hipFuncAttributeMaxDynamicSharedMemorySize, lds_bytes);
    k_main_npw<<<dim3(128, 2), dim3(512), lds_bytes, stream>>>(
        d_in[1], d_in[16], wdecf, d_out, flag);
  }
}